// Round 6
// baseline (1495.869 us; speedup 1.0000x reference)
//
#include <hip/hip_runtime.h>
#include <hip/hip_cooperative_groups.h>

namespace cg = cooperative_groups;

#define T_ 8
#define N_ 50000
#define E_ 800000
#define C_ 64
#define OVF_CAP 131072
#define NB 196     // node buckets (256 nodes each, 196*256 = 50176 >= N)
#define NBLK 256   // edge chunks (256*3125 = 800000 exactly)
#define EPB 3125   // edges per chunk
#define SCN (2 * NB * NBLK)  // 100352 = 392 tiles x 256 (tile == row)
#define XCVT_UNITS 12500
#define WPREP_UNITS 64

typedef __attribute__((ext_vector_type(8))) short bf16x8;
typedef __attribute__((ext_vector_type(4))) float f32x4;

__device__ inline short f2bf(float f) {
    union { float f; unsigned int u; } v; v.f = f;
    unsigned int u = v.u + 0x7FFFu + ((v.u >> 16) & 1u);  // RNE
    return (short)(u >> 16);
}
__device__ inline float bf2f_lo(unsigned int u) {
    union { unsigned int u; float f; } v; v.u = u << 16;
    return v.f;
}
__device__ inline float bf2f_hi(unsigned int u) {
    union { unsigned int u; float f; } v; v.u = u & 0xffff0000u;
    return v.f;
}

// xcvt helper: convert one (n,t,c8) slice to node-major bf16 xb
__device__ inline void xcvt_step(int id, const float* __restrict__ x,
                                 unsigned short* __restrict__ xb) {
    int c8 = id & 7;
    int t = (id >> 3) & 7;
    int n = id >> 6;
    const float* xr = x + ((long long)t * N_ + n) * C_ + c8 * 8;
    float4 a = *(const float4*)(xr);
    float4 b = *(const float4*)(xr + 4);
    bf16x8 o;
    o[0] = f2bf(a.x); o[1] = f2bf(a.y); o[2] = f2bf(a.z); o[3] = f2bf(a.w);
    o[4] = f2bf(b.x); o[5] = f2bf(b.y); o[6] = f2bf(b.z); o[7] = f2bf(b.w);
    *(bf16x8*)(xb + (long long)id * 8) = o;  // node-major [n][t][c]
}

struct CoopParams {
    const int* src; const int* dst; const float* w;
    const float* x;
    const float* Wz0; const float* Wz1; const float* Wh0; const float* Wh1;
    int* counts; int* tsum; int* soff;
    int2* rec;
    float* degw; int* cnt;
    int2* es; int cap;
    int* ovfcnt; int4* ovf;
    unsigned short* xb; short* swz;
};

// ---------------------------------------------------------------------------
// ONE cooperative kernel replaces hist/xcvt/wprep/scanA/scanB/scatter/degw/
// esbuild (6 launches + memset -> 1 launch, zero inter-kernel drains).
// All phases are block-stride (any grid size); grid.sync() between phases.
__global__ __launch_bounds__(256, 8) void coop_prep_kernel(CoopParams p) {
    cg::grid_group grid = cg::this_grid();
    int tid = threadIdx.x;
    int bid = blockIdx.x;
    int G = gridDim.x;

    __shared__ int h[2 * NB];     // hist / scatter offsets
    __shared__ int sc[520];       // scan scratch
    __shared__ float facc[256];   // degw accumulate
    __shared__ int cl[256];       // esbuild rank counters
    __shared__ float di[256];     // esbuild dinv[dst] cache

    // ---- phase 1: hist chunks + xcvt + wprep + ovfcnt init ----
    if (bid == 0 && tid == 0) *p.ovfcnt = 0;
    for (int c = bid; c < NBLK; c += G) {
        for (int i = tid; i < 2 * NB; i += 256) h[i] = 0;
        __syncthreads();
        int e0 = c * EPB;
        for (int j = tid; j < EPB; j += 256) {
            int e = e0 + j;
            atomicAdd(&h[p.src[e] >> 8], 1);
            atomicAdd(&h[NB + (p.dst[e] >> 8)], 1);
        }
        __syncthreads();
        for (int i = tid; i < 2 * NB; i += 256)
            p.counts[i * NBLK + c] = h[i];
        __syncthreads();
    }
    for (int u = bid; u < XCVT_UNITS + WPREP_UNITS; u += G) {
        if (u < XCVT_UNITS) {
            xcvt_step(u * 256 + tid, p.x, p.xb);
        } else {
            int idx = (u - XCVT_UNITS) * 256 + tid;  // < 16384
            int j = idx & 7;
            int lane = (idx >> 3) & 63;
            int kb = (idx >> 9) & 1;
            int cc = (idx >> 10) & 3;
            int mat = idx >> 12;
            const float* W = (mat == 0) ? p.Wz0 : (mat == 1) ? p.Wz1
                            : (mat == 2) ? p.Wh0 : p.Wh1;
            int k = kb * 32 + (lane >> 4) * 8 + j;
            int n = cc * 16 + (lane & 15);
            p.swz[idx] = f2bf(W[k * 64 + n]);
        }
    }
    grid.sync();

    // ---- phase 2: per-tile exclusive scan (tile t = row t, 256 entries) ----
    for (int t = bid; t < 2 * NB; t += G) {
        int v = p.counts[t * 256 + tid];
        int orig = v;
        int lane = tid & 63, wv = tid >> 6;
#pragma unroll
        for (int off = 1; off < 64; off <<= 1) {
            int u = __shfl_up(v, off);
            if (lane >= off) v += u;
        }
        if (lane == 63) sc[wv] = v;
        __syncthreads();
        if (tid == 0) {
            int s = 0;
#pragma unroll
            for (int i = 0; i < 4; ++i) { int x2 = sc[i]; sc[i] = s; s += x2; }
            sc[4] = s;
        }
        __syncthreads();
        p.counts[t * 256 + tid] = sc[wv] + v - orig;  // exclusive within tile
        if (tid == 0) p.tsum[t] = sc[4];
        __syncthreads();
    }
    grid.sync();

    // ---- phase 3: exclusive scan of 392 tile totals -> soff ----
    if (bid == 0) {
        int i0 = 2 * tid, i1 = 2 * tid + 1;
        int v0 = (i0 < 2 * NB) ? p.tsum[i0] : 0;
        int v1 = (i1 < 2 * NB) ? p.tsum[i1] : 0;
        int pr = v0 + v1;
        int v = pr;
        int lane = tid & 63, wv = tid >> 6;
#pragma unroll
        for (int off = 1; off < 64; off <<= 1) {
            int u = __shfl_up(v, off);
            if (lane >= off) v += u;
        }
        if (lane == 63) sc[wv] = v;
        __syncthreads();
        if (tid == 0) {
            int s = 0;
#pragma unroll
            for (int i = 0; i < 4; ++i) { int x2 = sc[i]; sc[i] = s; s += x2; }
        }
        __syncthreads();
        int excl = sc[wv] + v - pr;
        if (i0 < 2 * NB) p.soff[i0] = excl;
        if (i1 < 2 * NB) p.soff[i1] = excl + v0;
    }
    grid.sync();

    // ---- phase 4: deterministic LDS-ranked scatter (no global atomics) ----
    // global base for (row i, chunk c) = counts[i*NBLK+c] + soff[i]
    for (int c = bid; c < NBLK; c += G) {
        for (int i = tid; i < 2 * NB; i += 256)
            h[i] = p.counts[i * NBLK + c] + p.soff[i];
        __syncthreads();
        int e0 = c * EPB;
        for (int j = tid; j < EPB; j += 256) {
            int e = e0 + j;
            int s = p.src[e], d = p.dst[e];
            float wv = p.w[e];
            int r0 = atomicAdd(&h[s >> 8], 1);              // LDS atomic
            p.rec[r0] = make_int2(s, __float_as_int(wv));
            int r1 = atomicAdd(&h[NB + (d >> 8)], 1);       // LDS atomic
            p.rec[r1] = make_int2(s | ((d & 255) << 16), __float_as_int(wv));
        }
        __syncthreads();
    }
    grid.sync();

    // ---- phase 5: degw = per-bucket segmented sum of src-keyed records ----
    for (int b = bid; b < NB; b += G) {
        facc[tid] = 0.f;
        __syncthreads();
        int s0 = p.counts[b * 256] + p.soff[b];
        int s1 = (b == NB - 1) ? E_ : (p.counts[(b + 1) * 256] + p.soff[b + 1]);
        for (int j = s0 + tid; j < s1; j += 256) {
            int2 r = p.rec[j];
            atomicAdd(&facc[r.x & 255], __int_as_float(r.y));  // LDS fp32
        }
        __syncthreads();
        int node = b * 256 + tid;
        if (node < N_) p.degw[node] = facc[tid];
        __syncthreads();
    }
    grid.sync();

    // ---- phase 6: es buckets + cnt from dst-keyed records, nw inline ----
    for (int b = bid; b < NB; b += G) {
        cl[tid] = 0;
        int node = b * 256 + tid;
        float dd = (node < N_) ? p.degw[node] : 0.f;
        di[tid] = dd > 0.f ? rsqrtf(fmaxf(dd, 1e-12f)) : 0.f;
        __syncthreads();
        int s0 = p.counts[(NB + b) * 256] + p.soff[NB + b];
        int s1 = (b == NB - 1) ? 2 * E_
                               : (p.counts[(NB + b + 1) * 256] + p.soff[NB + b + 1]);
        for (int j = s0 + tid; j < s1; j += 256) {
            int2 r = p.rec[j];
            int s = r.x & 0xffff;          // src < 50000 fits 16 bits
            int dl = (r.x >> 16) & 255;
            float ds = p.degw[s];          // L2-resident random read
            float is = ds > 0.f ? rsqrtf(fmaxf(ds, 1e-12f)) : 0.f;
            float nwv = -__int_as_float(r.y) * is * di[dl];
            int rank = atomicAdd(&cl[dl], 1);  // LDS atomic
            int d = b * 256 + dl;
            if (rank < p.cap) {
                p.es[d * p.cap + rank] = make_int2(s, __float_as_int(nwv));
            } else {
                int op = atomicAdd(p.ovfcnt, 1);
                if (op < OVF_CAP) p.ovf[op] = make_int4(d, s, __float_as_int(nwv), 0);
            }
        }
        __syncthreads();
        if (node < N_) p.cnt[node] = cl[tid];
        __syncthreads();
    }
}

// accumulate one weighted bf16x8 row-slice into acc[8]
#define ACC8(W, V)                                                       \
    acc[0] += (W) * bf2f_lo((V).x); acc[1] += (W) * bf2f_hi((V).x);      \
    acc[2] += (W) * bf2f_lo((V).y); acc[3] += (W) * bf2f_hi((V).y);      \
    acc[4] += (W) * bf2f_lo((V).z); acc[5] += (W) * bf2f_hi((V).z);      \
    acc[6] += (W) * bf2f_lo((V).w); acc[7] += (W) * bf2f_hi((V).w);

// gather + node kernel — byte-identical to R5's verified structure.
__global__ __launch_bounds__(256) void gather_node_kernel(
        const int* __restrict__ cnt, const int2* __restrict__ es, int cap,
        const int* __restrict__ ovfcnt, const int4* __restrict__ ovf,
        const unsigned short* __restrict__ xb, const short* __restrict__ swz,
        const float* __restrict__ bxz, const float* __restrict__ bhz,
        const float* __restrict__ bxh, const float* __restrict__ bhh,
        const float* __restrict__ Wlin, const float* __restrict__ blin,
        float* __restrict__ out) {
    __shared__ unsigned short ltx[32 * 72];  // 32 rows x 64 ch bf16, +8 pad
    __shared__ float laz[2][16][65];         // az exchange, +1 pad

    int lane = threadIdx.x & 63;
    int wid = threadIdx.x >> 6;
    int base = blockIdx.x * 4;

    // ---- phase 1: gather node d = base + wid (lane = t*8 + oct) ----
    {
        int d = base + wid;
        int t = lane >> 3;
        int oct = lane & 7;
        int2 pk = (lane < cap) ? es[d * cap + lane] : make_int2(0, 0);
        int m = cnt[d];
        int mb = m < cap ? m : cap;

        float acc[8] = {0.f, 0.f, 0.f, 0.f, 0.f, 0.f, 0.f, 0.f};
        const unsigned short* xbase = xb + lane * 8;  // node record = 512 shorts
        int k = 0;
        for (; k + 3 < mb; k += 4) {
            int s0 = __shfl(pk.x, k);
            int s1 = __shfl(pk.x, k + 1);
            int s2 = __shfl(pk.x, k + 2);
            int s3 = __shfl(pk.x, k + 3);
            uint4 v0 = *(const uint4*)(xbase + (long long)s0 * 512);
            uint4 v1 = *(const uint4*)(xbase + (long long)s1 * 512);
            uint4 v2 = *(const uint4*)(xbase + (long long)s2 * 512);
            uint4 v3 = *(const uint4*)(xbase + (long long)s3 * 512);
            float w0 = __int_as_float(__shfl(pk.y, k));
            float w1 = __int_as_float(__shfl(pk.y, k + 1));
            float w2 = __int_as_float(__shfl(pk.y, k + 2));
            float w3 = __int_as_float(__shfl(pk.y, k + 3));
            ACC8(w0, v0);
            ACC8(w1, v1);
            ACC8(w2, v2);
            ACC8(w3, v3);
        }
        for (; k < mb; ++k) {
            int s0 = __shfl(pk.x, k);
            float w0 = __int_as_float(__shfl(pk.y, k));
            uint4 v0 = *(const uint4*)(xbase + (long long)s0 * 512);
            ACC8(w0, v0);
        }
        if (m > cap) {  // overflow path: never taken for this input
            int oc = *ovfcnt;
            if (oc > OVF_CAP) oc = OVF_CAP;
            for (int i = 0; i < oc; ++i) {
                int4 o = ovf[i];  // uniform addr -> broadcast
                if (o.x == d) {
                    float w0 = __int_as_float(o.z);
                    uint4 v0 = *(const uint4*)(xbase + (long long)o.y * 512);
                    ACC8(w0, v0);
                }
            }
        }
        uint4 ob;
        ob.x = (unsigned int)(unsigned short)f2bf(acc[0]) |
               ((unsigned int)(unsigned short)f2bf(acc[1]) << 16);
        ob.y = (unsigned int)(unsigned short)f2bf(acc[2]) |
               ((unsigned int)(unsigned short)f2bf(acc[3]) << 16);
        ob.z = (unsigned int)(unsigned short)f2bf(acc[4]) |
               ((unsigned int)(unsigned short)f2bf(acc[5]) << 16);
        ob.w = (unsigned int)(unsigned short)f2bf(acc[6]) |
               ((unsigned int)(unsigned short)f2bf(acc[7]) << 16);
        int r = wid * 8 + t;  // block-row: r>>3 = node, r&7 = t
        *(uint4*)(ltx + r * 72 + oct * 8) = ob;
    }
    __syncthreads();

    // ---- phase 2: MFMA. wave -> (M-tile mt, gate g: 0=az, 1=ah) ----
    int mt = wid >> 1;
    int g = wid & 1;
    int c16 = lane & 15;
    int kq = lane >> 4;
    int r_blk = mt * 16 + c16;
    const unsigned short* xr = xb + (long long)(base * 8 + r_blk) * C_ + kq * 8;
    bf16x8 ax0 = *(const bf16x8*)(xr);
    bf16x8 ax1 = *(const bf16x8*)(xr + 32);
    bf16x8 at0 = *(const bf16x8*)(ltx + r_blk * 72 + kq * 8);
    bf16x8 at1 = *(const bf16x8*)(ltx + r_blk * 72 + 32 + kq * 8);

    const float* bA = g ? bxh : bxz;
    const float* bB = g ? bhh : bhz;
    const short* wA = swz + (2 * g) * 4096 + lane * 8;      // x-weight frags
    const short* wB = swz + (2 * g + 1) * 4096 + lane * 8;  // tx1-weight frags

    f32x4 a4[4];
#pragma unroll
    for (int c = 0; c < 4; ++c) {
        int col = c * 16 + c16;
        float bv = bA[col] + bB[col];
        a4[c] = (f32x4){bv, bv, bv, bv};
    }
#pragma unroll
    for (int c = 0; c < 4; ++c) {
        bf16x8 bA0 = *(const bf16x8*)(wA + (c * 2 + 0) * 512);
        bf16x8 bA1 = *(const bf16x8*)(wA + (c * 2 + 1) * 512);
        bf16x8 bB0 = *(const bf16x8*)(wB + (c * 2 + 0) * 512);
        bf16x8 bB1 = *(const bf16x8*)(wB + (c * 2 + 1) * 512);
        a4[c] = __builtin_amdgcn_mfma_f32_16x16x32_bf16(ax0, bA0, a4[c], 0, 0, 0);
        a4[c] = __builtin_amdgcn_mfma_f32_16x16x32_bf16(ax1, bA1, a4[c], 0, 0, 0);
        a4[c] = __builtin_amdgcn_mfma_f32_16x16x32_bf16(at0, bB0, a4[c], 0, 0, 0);
        a4[c] = __builtin_amdgcn_mfma_f32_16x16x32_bf16(at1, bB1, a4[c], 0, 0, 0);
    }

    // ---- phase 3: az -> LDS; ah-wave computes epilogue ----
    if (g == 0) {
#pragma unroll
        for (int c = 0; c < 4; ++c)
#pragma unroll
            for (int r = 0; r < 4; ++r)
                laz[mt][kq * 4 + r][c * 16 + c16] = a4[c][r];
    }
    __syncthreads();
    if (g == 1) {
        float part[4] = {0.f, 0.f, 0.f, 0.f};
#pragma unroll
        for (int c = 0; c < 4; ++c) {
            int col = c * 16 + c16;
            float wl = Wlin[col];
#pragma unroll
            for (int r = 0; r < 4; ++r) {
                float a = laz[mt][kq * 4 + r][col];
                float b = a4[c][r];
                float z = 1.f / (1.f + __expf(-a));
                float aa = fabsf(b);
                float e = __expf(-2.f * aa);
                float ht = copysignf((1.f - e) / (1.f + e), b);
                float h2 = fmaxf((1.f - z) * ht, 0.f);
                part[r] += h2 * wl;
            }
        }
#pragma unroll
        for (int m = 1; m <= 8; m <<= 1) {
#pragma unroll
            for (int r = 0; r < 4; ++r) part[r] += __shfl_xor(part[r], m);
        }
        if (c16 == 0) {
            float bl = blin[0];
#pragma unroll
            for (int r = 0; r < 4; ++r) {
                int rb = mt * 16 + kq * 4 + r;
                out[(long long)(rb & 7) * N_ + base + (rb >> 3)] = part[r] + bl;
            }
        }
    }
}

extern "C" void kernel_launch(void* const* d_in, const int* in_sizes, int n_in,
                              void* d_out, int out_size, void* d_ws, size_t ws_size,
                              hipStream_t stream) {
    const float* x    = (const float*)d_in[0];
    const int*   ei   = (const int*)d_in[1];
    const float* w    = (const float*)d_in[2];
    const float* Wxz0 = (const float*)d_in[3];
    const float* Wxz1 = (const float*)d_in[4];
    const float* bxz  = (const float*)d_in[5];
    const float* bhz  = (const float*)d_in[8];
    const float* Wxh0 = (const float*)d_in[15];
    const float* Wxh1 = (const float*)d_in[16];
    const float* bxh  = (const float*)d_in[17];
    const float* bhh  = (const float*)d_in[20];
    const float* Wlin = (const float*)d_in[21];
    const float* blin = (const float*)d_in[22];
    float* out = (float*)d_out;

    const int* src = ei;
    const int* dst = ei + E_;

    // workspace layout (512-aligned blocks):
    char* ws = (char*)d_ws;
    size_t off = 0;
    auto alloc = [&](size_t bytes) {
        char* p = ws + off;
        off = (off + bytes + 511) & ~(size_t)511;
        return p;
    };
    short* swz         = (short*)alloc(4 * 4096 * sizeof(short));           // 32 KB
    float* degw        = (float*)alloc((size_t)N_ * 4);                     // 200 KB
    int*   cnt         = (int*)alloc((size_t)N_ * 4);                       // 200 KB
    int*   ovfcnt      = (int*)alloc(512);
    int4*  ovf         = (int4*)alloc((size_t)OVF_CAP * 16);                // 2 MB
    int*   counts      = (int*)alloc((size_t)SCN * 4);                      // 401 KB
    int*   tsum        = (int*)alloc((size_t)2 * NB * 4);
    int*   soff        = (int*)alloc((size_t)2 * NB * 4);
    int2*  rec         = (int2*)alloc((size_t)2 * E_ * 8);                  // 12.8 MB
    unsigned short* xb = (unsigned short*)alloc((size_t)T_ * N_ * C_ * 2);  // 51.2 MB
    size_t fixed = off;

    // pick the largest bucket capacity that fits the workspace
    int cap = 16;
    for (int c : {64, 48, 32, 24}) {
        if (fixed + (size_t)N_ * c * 8 + 512 <= ws_size) { cap = c; break; }
    }
    int2* es = (int2*)alloc((size_t)N_ * cap * 8);

    // cooperative grid size: resident-by-construction (occupancy query, cached)
    static int coopGrid = 0;
    if (coopGrid == 0) {
        int dev = 0;
        hipGetDevice(&dev);
        hipDeviceProp_t prop;
        hipGetDeviceProperties(&prop, dev);
        int occ = 0;
        hipOccupancyMaxActiveBlocksPerMultiprocessor(&occ, coop_prep_kernel, 256, 0);
        if (occ < 1) occ = 1;
        long long g = (long long)occ * prop.multiProcessorCount;
        if (g > 2048) g = 2048;
        if (g < 1) g = 1;
        coopGrid = (int)g;
    }

    CoopParams p;
    p.src = src; p.dst = dst; p.w = w; p.x = x;
    p.Wz0 = Wxz0; p.Wz1 = Wxz1; p.Wh0 = Wxh0; p.Wh1 = Wxh1;
    p.counts = counts; p.tsum = tsum; p.soff = soff;
    p.rec = rec; p.degw = degw; p.cnt = cnt;
    p.es = es; p.cap = cap;
    p.ovfcnt = ovfcnt; p.ovf = ovf;
    p.xb = xb; p.swz = swz;

    void* args[] = {&p};
    hipLaunchCooperativeKernel(coop_prep_kernel, dim3(coopGrid), dim3(256),
                               args, 0, stream);

    // gather: 12500 blocks x 4 nodes = 50000
    gather_node_kernel<<<N_ / 4, 256, 0, stream>>>(
        cnt, es, cap, ovfcnt, ovf, xb, swz,
        bxz, bhz, bxh, bhh, Wlin, blin, out);
}

// Round 7
// 373.279 us; speedup vs baseline: 4.0074x; 4.0074x over previous
//
#include <hip/hip_runtime.h>

#define T_ 8
#define N_ 50000
#define E_ 800000
#define C_ 64
#define OVF_CAP 131072
#define NB 196     // node buckets (256 nodes each, 196*256 = 50176 >= N)
#define NBLK 256   // edge chunks (256*3125 = 800000 exactly)
#define EPB 3125   // edges per chunk
#define SCN (2 * NB * NBLK)  // 100352 = 49 * 2048 exactly
#define SCAN_TILES 49
// xcvt spread: 12500 units total, apportioned across the dependency chain
#define XC1 4500   // in prep (with hist + wprep)
#define XC4 4000   // in scatter
#define XC5 2000   // in degw
#define XC6 2000   // in esbuild

typedef __attribute__((ext_vector_type(8))) short bf16x8;
typedef __attribute__((ext_vector_type(4))) float f32x4;

__device__ inline short f2bf(float f) {
    union { float f; unsigned int u; } v; v.f = f;
    unsigned int u = v.u + 0x7FFFu + ((v.u >> 16) & 1u);  // RNE
    return (short)(u >> 16);
}
__device__ inline float bf2f_lo(unsigned int u) {
    union { unsigned int u; float f; } v; v.u = u << 16;
    return v.f;
}
__device__ inline float bf2f_hi(unsigned int u) {
    union { unsigned int u; float f; } v; v.u = u & 0xffff0000u;
    return v.f;
}

// xcvt helper: convert one (n,t,c8) slice to node-major bf16 xb
__device__ inline void xcvt_step(int id, const float* __restrict__ x,
                                 unsigned short* __restrict__ xb) {
    int c8 = id & 7;
    int t = (id >> 3) & 7;
    int n = id >> 6;
    const float* xr = x + ((long long)t * N_ + n) * C_ + c8 * 8;
    float4 a = *(const float4*)(xr);
    float4 b = *(const float4*)(xr + 4);
    bf16x8 o;
    o[0] = f2bf(a.x); o[1] = f2bf(a.y); o[2] = f2bf(a.z); o[3] = f2bf(a.w);
    o[4] = f2bf(b.x); o[5] = f2bf(b.y); o[6] = f2bf(b.z); o[7] = f2bf(b.w);
    *(bf16x8*)(xb + (long long)id * 8) = o;  // node-major [n][t][c]
}

// ---------------------------------------------------------------------------
// K1: bucket histograms (LDS atomics) + xcvt part 1 + wprep.
__global__ __launch_bounds__(256) void prep_kernel(
        const int* __restrict__ src, const int* __restrict__ dst,
        int* __restrict__ counts,
        const float* __restrict__ x, unsigned short* __restrict__ xb,
        const float* __restrict__ Wz0, const float* __restrict__ Wz1,
        const float* __restrict__ Wh0, const float* __restrict__ Wh1,
        short* __restrict__ swz) {
    if (blockIdx.x < NBLK) {
        __shared__ int h[2 * NB];
        int t = threadIdx.x;
        for (int i = t; i < 2 * NB; i += 256) h[i] = 0;
        __syncthreads();
        int e0 = blockIdx.x * EPB;
        for (int j = t; j < EPB; j += 256) {
            int e = e0 + j;
            atomicAdd(&h[src[e] >> 8], 1);
            atomicAdd(&h[NB + (dst[e] >> 8)], 1);
        }
        __syncthreads();
        for (int i = t; i < 2 * NB; i += 256)
            counts[i * NBLK + blockIdx.x] = h[i];
    } else if (blockIdx.x < NBLK + XC1) {
        int id = (blockIdx.x - NBLK) * 256 + threadIdx.x;
        xcvt_step(id, x, xb);
    } else {
        int idx = (blockIdx.x - NBLK - XC1) * 256 + threadIdx.x;  // < 16384
        int j = idx & 7;
        int lane = (idx >> 3) & 63;
        int kb = (idx >> 9) & 1;
        int c = (idx >> 10) & 3;
        int mat = idx >> 12;
        const float* W = (mat == 0) ? Wz0 : (mat == 1) ? Wz1 : (mat == 2) ? Wh0 : Wh1;
        int k = kb * 32 + (lane >> 4) * 8 + j;
        int n = c * 16 + (lane & 15);
        swz[idx] = f2bf(W[k * 64 + n]);
    }
}

// K2: scan pass A over the 100352 counts (49 tiles x 2048, exact).
__global__ __launch_bounds__(1024) void scan_a_kernel(int* __restrict__ cnts,
                                                      int* __restrict__ tsum) {
    __shared__ int wsum[16];
    int tid = threadIdx.x, lane = tid & 63, wid = tid >> 6;
    int i0 = blockIdx.x * 2048 + tid * 2;
    int v0 = cnts[i0], v1 = cnts[i0 + 1];
    int orig = v0 + v1;
    int v = orig;
#pragma unroll
    for (int off = 1; off < 64; off <<= 1) {
        int u = __shfl_up(v, off);
        if (lane >= off) v += u;
    }
    if (lane == 63) wsum[wid] = v;
    __syncthreads();
    if (wid == 0) {
        int s = (lane < 16) ? wsum[lane] : 0;
#pragma unroll
        for (int off = 1; off < 16; off <<= 1) {
            int u = __shfl_up(s, off);
            if (lane >= off) s += u;
        }
        if (lane < 16) wsum[lane] = s;
    }
    __syncthreads();
    int wpre = wid ? wsum[wid - 1] : 0;
    int ex = wpre + v - orig;  // exclusive prefix of this thread's pair
    cnts[i0] = ex;
    cnts[i0 + 1] = ex + v0;
    if (tid == 0) tsum[blockIdx.x] = wsum[15];
}

// K3: pass B — every block redundantly scans the 49 tile totals, adds offset.
//     Also zero-inits ovfcnt (replaces a memset dispatch).
__global__ __launch_bounds__(1024) void scan_b_kernel(const int* __restrict__ tsum,
                                                      int* __restrict__ cnts,
                                                      int* __restrict__ ovfcnt) {
    __shared__ int soff[SCAN_TILES];
    int tid = threadIdx.x, lane = tid & 63, wid = tid >> 6;
    if (blockIdx.x == 0 && tid == 0) *ovfcnt = 0;
    if (wid == 0) {
        int own = (lane < SCAN_TILES) ? tsum[lane] : 0;
        int s = own;
#pragma unroll
        for (int off = 1; off < 64; off <<= 1) {
            int u = __shfl_up(s, off);
            if (lane >= off) s += u;
        }
        if (lane < SCAN_TILES) soff[lane] = s - own;  // exclusive
    }
    __syncthreads();
    int off = soff[blockIdx.x];
    int i0 = blockIdx.x * 2048 + tid;
    cnts[i0] += off;
    cnts[i0 + 1024] += off;
}

// K4: deterministic LDS-ranked scatter (zero global atomics) + xcvt part 2.
__global__ __launch_bounds__(256) void scatter_kernel(
        const int* __restrict__ src, const int* __restrict__ dst,
        const float* __restrict__ w, const int* __restrict__ scn,
        int2* __restrict__ rec,
        const float* __restrict__ x, unsigned short* __restrict__ xb) {
    if (blockIdx.x < NBLK) {
        __shared__ int offs[2 * NB];
        int t = threadIdx.x;
        for (int i = t; i < 2 * NB; i += 256)
            offs[i] = scn[i * NBLK + blockIdx.x];
        __syncthreads();
        int e0 = blockIdx.x * EPB;
        for (int j = t; j < EPB; j += 256) {
            int e = e0 + j;
            int s = src[e], d = dst[e];
            float wv = w[e];
            int r0 = atomicAdd(&offs[s >> 8], 1);           // LDS atomic
            rec[r0] = make_int2(s, __float_as_int(wv));
            int r1 = atomicAdd(&offs[NB + (d >> 8)], 1);    // LDS atomic
            rec[r1] = make_int2(s | ((d & 255) << 16), __float_as_int(wv));
        }
    } else {
        int id = (XC1 + blockIdx.x - NBLK) * 256 + threadIdx.x;
        xcvt_step(id, x, xb);
    }
}

// K5: degw = per-bucket segmented sum of src-keyed records + xcvt part 3.
__global__ __launch_bounds__(256) void degw_kernel(
        const int2* __restrict__ rec, const int* __restrict__ scn,
        float* __restrict__ degw,
        const float* __restrict__ x, unsigned short* __restrict__ xb) {
    if (blockIdx.x < NB) {
        __shared__ float acc[256];
        int t = threadIdx.x, b = blockIdx.x;
        acc[t] = 0.f;
        __syncthreads();
        int s0 = scn[b * NBLK];
        int s1 = (b == NB - 1) ? E_ : scn[(b + 1) * NBLK];
        for (int j = s0 + t; j < s1; j += 256) {
            int2 r = rec[j];
            atomicAdd(&acc[r.x & 255], __int_as_float(r.y));  // LDS fp32 atomic
        }
        __syncthreads();
        int node = b * 256 + t;
        if (node < N_) degw[node] = acc[t];
    } else {
        int id = (XC1 + XC4 + blockIdx.x - NB) * 256 + threadIdx.x;
        xcvt_step(id, x, xb);
    }
}

// K6: es buckets + cnt from dst-keyed records (nw inline) + xcvt part 4.
__global__ __launch_bounds__(256) void esbuild_kernel(
        const int2* __restrict__ rec, const int* __restrict__ scn,
        const float* __restrict__ degw, int* __restrict__ cnt,
        int2* __restrict__ es, int cap,
        int* __restrict__ ovfcnt, int4* __restrict__ ovf,
        const float* __restrict__ x, unsigned short* __restrict__ xb) {
    if (blockIdx.x < NB) {
        __shared__ int cl[256];
        __shared__ float di[256];
        int t = threadIdx.x, b = blockIdx.x;
        cl[t] = 0;
        int node = b * 256 + t;
        float dd = (node < N_) ? degw[node] : 0.f;
        di[t] = dd > 0.f ? rsqrtf(fmaxf(dd, 1e-12f)) : 0.f;
        __syncthreads();
        int s0 = scn[(NB + b) * NBLK];
        int s1 = (b == NB - 1) ? 2 * E_ : scn[(NB + b + 1) * NBLK];
        for (int j = s0 + t; j < s1; j += 256) {
            int2 r = rec[j];
            int s = r.x & 0xffff;          // src < 50000 fits 16 bits
            int dl = (r.x >> 16) & 255;
            float ds = degw[s];            // L2-resident random read
            float is = ds > 0.f ? rsqrtf(fmaxf(ds, 1e-12f)) : 0.f;
            float nwv = -__int_as_float(r.y) * is * di[dl];
            int rank = atomicAdd(&cl[dl], 1);  // LDS atomic
            int d = b * 256 + dl;
            if (rank < cap) {
                es[d * cap + rank] = make_int2(s, __float_as_int(nwv));
            } else {
                int op = atomicAdd(ovfcnt, 1);
                if (op < OVF_CAP) ovf[op] = make_int4(d, s, __float_as_int(nwv), 0);
            }
        }
        __syncthreads();
        if (node < N_) cnt[node] = cl[t];
    } else {
        int id = (XC1 + XC4 + XC5 + blockIdx.x - NB) * 256 + threadIdx.x;
        xcvt_step(id, x, xb);
    }
}

// accumulate one weighted bf16x8 row-slice into acc[8]
#define ACC8(W, V)                                                       \
    acc[0] += (W) * bf2f_lo((V).x); acc[1] += (W) * bf2f_hi((V).x);      \
    acc[2] += (W) * bf2f_lo((V).y); acc[3] += (W) * bf2f_hi((V).y);      \
    acc[4] += (W) * bf2f_lo((V).z); acc[5] += (W) * bf2f_hi((V).z);      \
    acc[6] += (W) * bf2f_lo((V).w); acc[7] += (W) * bf2f_hi((V).w);

// K7: FUSED gather + node (R5 structure; inner loop deepened to 8-in-flight).
__global__ __launch_bounds__(256) void gather_node_kernel(
        const int* __restrict__ cnt, const int2* __restrict__ es, int cap,
        const int* __restrict__ ovfcnt, const int4* __restrict__ ovf,
        const unsigned short* __restrict__ xb, const short* __restrict__ swz,
        const float* __restrict__ bxz, const float* __restrict__ bhz,
        const float* __restrict__ bxh, const float* __restrict__ bhh,
        const float* __restrict__ Wlin, const float* __restrict__ blin,
        float* __restrict__ out) {
    __shared__ unsigned short ltx[32 * 72];  // 32 rows x 64 ch bf16, +8 pad
    __shared__ float laz[2][16][65];         // az exchange, +1 pad

    int lane = threadIdx.x & 63;
    int wid = threadIdx.x >> 6;
    int base = blockIdx.x * 4;

    // ---- phase 1: gather node d = base + wid (lane = t*8 + oct) ----
    {
        int d = base + wid;
        int t = lane >> 3;
        int oct = lane & 7;
        int2 pk = (lane < cap) ? es[d * cap + lane] : make_int2(0, 0);
        int m = cnt[d];
        int mb = m < cap ? m : cap;

        float acc[8] = {0.f, 0.f, 0.f, 0.f, 0.f, 0.f, 0.f, 0.f};
        const unsigned short* xbase = xb + lane * 8;  // node record = 512 shorts
        int k = 0;
        for (; k + 7 < mb; k += 8) {  // 8 loads in flight per wave
            int ss[8];
#pragma unroll
            for (int j = 0; j < 8; ++j) ss[j] = __shfl(pk.x, k + j);
            uint4 vv[8];
#pragma unroll
            for (int j = 0; j < 8; ++j)
                vv[j] = *(const uint4*)(xbase + (long long)ss[j] * 512);
            float ww[8];
#pragma unroll
            for (int j = 0; j < 8; ++j)
                ww[j] = __int_as_float(__shfl(pk.y, k + j));
#pragma unroll
            for (int j = 0; j < 8; ++j) { ACC8(ww[j], vv[j]); }
        }
        for (; k + 3 < mb; k += 4) {
            int s0 = __shfl(pk.x, k);
            int s1 = __shfl(pk.x, k + 1);
            int s2 = __shfl(pk.x, k + 2);
            int s3 = __shfl(pk.x, k + 3);
            uint4 v0 = *(const uint4*)(xbase + (long long)s0 * 512);
            uint4 v1 = *(const uint4*)(xbase + (long long)s1 * 512);
            uint4 v2 = *(const uint4*)(xbase + (long long)s2 * 512);
            uint4 v3 = *(const uint4*)(xbase + (long long)s3 * 512);
            float w0 = __int_as_float(__shfl(pk.y, k));
            float w1 = __int_as_float(__shfl(pk.y, k + 1));
            float w2 = __int_as_float(__shfl(pk.y, k + 2));
            float w3 = __int_as_float(__shfl(pk.y, k + 3));
            ACC8(w0, v0);
            ACC8(w1, v1);
            ACC8(w2, v2);
            ACC8(w3, v3);
        }
        for (; k < mb; ++k) {
            int s0 = __shfl(pk.x, k);
            float w0 = __int_as_float(__shfl(pk.y, k));
            uint4 v0 = *(const uint4*)(xbase + (long long)s0 * 512);
            ACC8(w0, v0);
        }
        if (m > cap) {  // overflow path: never taken for this input
            int oc = *ovfcnt;
            if (oc > OVF_CAP) oc = OVF_CAP;
            for (int i = 0; i < oc; ++i) {
                int4 o = ovf[i];  // uniform addr -> broadcast
                if (o.x == d) {
                    float w0 = __int_as_float(o.z);
                    uint4 v0 = *(const uint4*)(xbase + (long long)o.y * 512);
                    ACC8(w0, v0);
                }
            }
        }
        uint4 ob;
        ob.x = (unsigned int)(unsigned short)f2bf(acc[0]) |
               ((unsigned int)(unsigned short)f2bf(acc[1]) << 16);
        ob.y = (unsigned int)(unsigned short)f2bf(acc[2]) |
               ((unsigned int)(unsigned short)f2bf(acc[3]) << 16);
        ob.z = (unsigned int)(unsigned short)f2bf(acc[4]) |
               ((unsigned int)(unsigned short)f2bf(acc[5]) << 16);
        ob.w = (unsigned int)(unsigned short)f2bf(acc[6]) |
               ((unsigned int)(unsigned short)f2bf(acc[7]) << 16);
        int r = wid * 8 + t;  // block-row: r>>3 = node, r&7 = t
        *(uint4*)(ltx + r * 72 + oct * 8) = ob;
    }
    __syncthreads();

    // ---- phase 2: MFMA. wave -> (M-tile mt, gate g: 0=az, 1=ah) ----
    int mt = wid >> 1;
    int g = wid & 1;
    int c16 = lane & 15;
    int kq = lane >> 4;
    int r_blk = mt * 16 + c16;
    const unsigned short* xr = xb + (long long)(base * 8 + r_blk) * C_ + kq * 8;
    bf16x8 ax0 = *(const bf16x8*)(xr);
    bf16x8 ax1 = *(const bf16x8*)(xr + 32);
    bf16x8 at0 = *(const bf16x8*)(ltx + r_blk * 72 + kq * 8);
    bf16x8 at1 = *(const bf16x8*)(ltx + r_blk * 72 + 32 + kq * 8);

    const float* bA = g ? bxh : bxz;
    const float* bB = g ? bhh : bhz;
    const short* wA = swz + (2 * g) * 4096 + lane * 8;      // x-weight frags
    const short* wB = swz + (2 * g + 1) * 4096 + lane * 8;  // tx1-weight frags

    f32x4 a4[4];
#pragma unroll
    for (int c = 0; c < 4; ++c) {
        int col = c * 16 + c16;
        float bv = bA[col] + bB[col];
        a4[c] = (f32x4){bv, bv, bv, bv};
    }
#pragma unroll
    for (int c = 0; c < 4; ++c) {
        bf16x8 bA0 = *(const bf16x8*)(wA + (c * 2 + 0) * 512);
        bf16x8 bA1 = *(const bf16x8*)(wA + (c * 2 + 1) * 512);
        bf16x8 bB0 = *(const bf16x8*)(wB + (c * 2 + 0) * 512);
        bf16x8 bB1 = *(const bf16x8*)(wB + (c * 2 + 1) * 512);
        a4[c] = __builtin_amdgcn_mfma_f32_16x16x32_bf16(ax0, bA0, a4[c], 0, 0, 0);
        a4[c] = __builtin_amdgcn_mfma_f32_16x16x32_bf16(ax1, bA1, a4[c], 0, 0, 0);
        a4[c] = __builtin_amdgcn_mfma_f32_16x16x32_bf16(at0, bB0, a4[c], 0, 0, 0);
        a4[c] = __builtin_amdgcn_mfma_f32_16x16x32_bf16(at1, bB1, a4[c], 0, 0, 0);
    }

    // ---- phase 3: az -> LDS; ah-wave computes epilogue ----
    if (g == 0) {
#pragma unroll
        for (int c = 0; c < 4; ++c)
#pragma unroll
            for (int r = 0; r < 4; ++r)
                laz[mt][kq * 4 + r][c * 16 + c16] = a4[c][r];
    }
    __syncthreads();
    if (g == 1) {
        float part[4] = {0.f, 0.f, 0.f, 0.f};
#pragma unroll
        for (int c = 0; c < 4; ++c) {
            int col = c * 16 + c16;
            float wl = Wlin[col];
#pragma unroll
            for (int r = 0; r < 4; ++r) {
                float a = laz[mt][kq * 4 + r][col];
                float b = a4[c][r];
                float z = 1.f / (1.f + __expf(-a));
                float aa = fabsf(b);
                float e = __expf(-2.f * aa);
                float ht = copysignf((1.f - e) / (1.f + e), b);
                float h = fmaxf((1.f - z) * ht, 0.f);
                part[r] += h * wl;
            }
        }
#pragma unroll
        for (int m = 1; m <= 8; m <<= 1) {
#pragma unroll
            for (int r = 0; r < 4; ++r) part[r] += __shfl_xor(part[r], m);
        }
        if (c16 == 0) {
            float bl = blin[0];
#pragma unroll
            for (int r = 0; r < 4; ++r) {
                int rb = mt * 16 + kq * 4 + r;
                out[(long long)(rb & 7) * N_ + base + (rb >> 3)] = part[r] + bl;
            }
        }
    }
}

extern "C" void kernel_launch(void* const* d_in, const int* in_sizes, int n_in,
                              void* d_out, int out_size, void* d_ws, size_t ws_size,
                              hipStream_t stream) {
    const float* x    = (const float*)d_in[0];
    const int*   ei   = (const int*)d_in[1];
    const float* w    = (const float*)d_in[2];
    const float* Wxz0 = (const float*)d_in[3];
    const float* Wxz1 = (const float*)d_in[4];
    const float* bxz  = (const float*)d_in[5];
    const float* bhz  = (const float*)d_in[8];
    const float* Wxh0 = (const float*)d_in[15];
    const float* Wxh1 = (const float*)d_in[16];
    const float* bxh  = (const float*)d_in[17];
    const float* bhh  = (const float*)d_in[20];
    const float* Wlin = (const float*)d_in[21];
    const float* blin = (const float*)d_in[22];
    float* out = (float*)d_out;

    const int* src = ei;
    const int* dst = ei + E_;

    // workspace layout (512-aligned blocks):
    char* ws = (char*)d_ws;
    size_t off = 0;
    auto alloc = [&](size_t bytes) {
        char* p = ws + off;
        off = (off + bytes + 511) & ~(size_t)511;
        return p;
    };
    short* swz         = (short*)alloc(4 * 4096 * sizeof(short));           // 32 KB
    float* degw        = (float*)alloc((size_t)N_ * 4);                     // 200 KB
    int*   cnt         = (int*)alloc((size_t)N_ * 4);                       // 200 KB
    int*   ovfcnt      = (int*)alloc(512);
    int4*  ovf         = (int4*)alloc((size_t)OVF_CAP * 16);                // 2 MB
    int*   counts      = (int*)alloc((size_t)SCN * 4);                      // 401 KB
    int*   tsum        = (int*)alloc((size_t)SCAN_TILES * 4);
    int2*  rec         = (int2*)alloc((size_t)2 * E_ * 8);                  // 12.8 MB
    unsigned short* xb = (unsigned short*)alloc((size_t)T_ * N_ * C_ * 2);  // 51.2 MB
    size_t fixed = off;

    // pick the largest bucket capacity that fits the workspace
    int cap = 16;
    for (int c : {64, 48, 32, 24}) {
        if (fixed + (size_t)N_ * c * 8 + 512 <= ws_size) { cap = c; break; }
    }
    int2* es = (int2*)alloc((size_t)N_ * cap * 8);

    // K1: hist (256) + xcvt part 1 (4500) + wprep (64)
    prep_kernel<<<NBLK + XC1 + 64, 256, 0, stream>>>(
        src, dst, counts, x, xb, Wxz0, Wxz1, Wxh0, Wxh1, swz);

    // K2/K3: exclusive scan of the 100352-entry count matrix (+ovfcnt init)
    scan_a_kernel<<<SCAN_TILES, 1024, 0, stream>>>(counts, tsum);
    scan_b_kernel<<<SCAN_TILES, 1024, 0, stream>>>(tsum, counts, ovfcnt);

    // K4: deterministic two-key scatter + xcvt part 2 (4000)
    scatter_kernel<<<NBLK + XC4, 256, 0, stream>>>(src, dst, w, counts, rec, x, xb);

    // K5: degw segmented reduce + xcvt part 3 (2000)
    degw_kernel<<<NB + XC5, 256, 0, stream>>>(rec, counts, degw, x, xb);

    // K6: es buckets + cnt + inline nw + xcvt part 4 (2000)
    esbuild_kernel<<<NB + XC6, 256, 0, stream>>>(rec, counts, degw, cnt,
                                                 es, cap, ovfcnt, ovf, x, xb);

    // K7: 12500 blocks x 4 nodes = 50000
    gather_node_kernel<<<N_ / 4, 256, 0, stream>>>(
        cnt, es, cap, ovfcnt, ovf, xb, swz,
        bxz, bhz, bxh, bhh, Wlin, blin, out);
}

// Round 8
// 367.923 us; speedup vs baseline: 4.0657x; 1.0146x over previous
//
#include <hip/hip_runtime.h>

#define T_ 8
#define N_ 50000
#define E_ 800000
#define C_ 64
#define OVF_CAP 131072
#define NB 196     // node buckets (256 nodes each, 196*256 = 50176 >= N)
#define NBLK 256   // edge chunks (256*3125 = 800000 exactly)
#define EPB 3125   // edges per chunk
#define SCN (2 * NB * NBLK)  // 100352 = 49 * 2048 exactly
#define SCAN_TILES 49

typedef __attribute__((ext_vector_type(8))) short bf16x8;
typedef __attribute__((ext_vector_type(4))) float f32x4;

__device__ inline short f2bf(float f) {
    union { float f; unsigned int u; } v; v.f = f;
    unsigned int u = v.u + 0x7FFFu + ((v.u >> 16) & 1u);  // RNE
    return (short)(u >> 16);
}
__device__ inline float bf2f_lo(unsigned int u) {
    union { unsigned int u; float f; } v; v.u = u << 16;
    return v.f;
}
__device__ inline float bf2f_hi(unsigned int u) {
    union { unsigned int u; float f; } v; v.u = u & 0xffff0000u;
    return v.f;
}

// xcvt helper: convert one (n,t,c8) slice to node-major bf16 xb
__device__ inline void xcvt_step(int id, const float* __restrict__ x,
                                 unsigned short* __restrict__ xb) {
    int c8 = id & 7;
    int t = (id >> 3) & 7;
    int n = id >> 6;
    const float* xr = x + ((long long)t * N_ + n) * C_ + c8 * 8;
    float4 a = *(const float4*)(xr);
    float4 b = *(const float4*)(xr + 4);
    bf16x8 o;
    o[0] = f2bf(a.x); o[1] = f2bf(a.y); o[2] = f2bf(a.z); o[3] = f2bf(a.w);
    o[4] = f2bf(b.x); o[5] = f2bf(b.y); o[6] = f2bf(b.z); o[7] = f2bf(b.w);
    *(bf16x8*)(xb + (long long)id * 8) = o;  // node-major [n][t][c]
}

// ---------------------------------------------------------------------------
// K1: bucket histograms (LDS atomics) + xcvt + wprep.
__global__ __launch_bounds__(256) void prep_kernel(
        const int* __restrict__ src, const int* __restrict__ dst,
        int* __restrict__ counts,
        const float* __restrict__ x, unsigned short* __restrict__ xb,
        const float* __restrict__ Wz0, const float* __restrict__ Wz1,
        const float* __restrict__ Wh0, const float* __restrict__ Wh1,
        short* __restrict__ swz) {
    if (blockIdx.x < NBLK) {
        __shared__ int h[2 * NB];
        int t = threadIdx.x;
        for (int i = t; i < 2 * NB; i += 256) h[i] = 0;
        __syncthreads();
        int e0 = blockIdx.x * EPB;
        for (int j = t; j < EPB; j += 256) {
            int e = e0 + j;
            atomicAdd(&h[src[e] >> 8], 1);
            atomicAdd(&h[NB + (dst[e] >> 8)], 1);
        }
        __syncthreads();
        for (int i = t; i < 2 * NB; i += 256)
            counts[i * NBLK + blockIdx.x] = h[i];
    } else if (blockIdx.x < NBLK + 12500) {
        int id = (blockIdx.x - NBLK) * 256 + threadIdx.x;
        xcvt_step(id, x, xb);
    } else {
        int idx = (blockIdx.x - NBLK - 12500) * 256 + threadIdx.x;  // < 16384
        int j = idx & 7;
        int lane = (idx >> 3) & 63;
        int kb = (idx >> 9) & 1;
        int c = (idx >> 10) & 3;
        int mat = idx >> 12;
        const float* W = (mat == 0) ? Wz0 : (mat == 1) ? Wz1 : (mat == 2) ? Wh0 : Wh1;
        int k = kb * 32 + (lane >> 4) * 8 + j;
        int n = c * 16 + (lane & 15);
        swz[idx] = f2bf(W[k * 64 + n]);
    }
}

// K2: scan pass A over the 100352 counts (49 tiles x 2048, exact).
__global__ __launch_bounds__(1024) void scan_a_kernel(int* __restrict__ cnts,
                                                      int* __restrict__ tsum) {
    __shared__ int wsum[16];
    int tid = threadIdx.x, lane = tid & 63, wid = tid >> 6;
    int i0 = blockIdx.x * 2048 + tid * 2;
    int v0 = cnts[i0], v1 = cnts[i0 + 1];
    int orig = v0 + v1;
    int v = orig;
#pragma unroll
    for (int off = 1; off < 64; off <<= 1) {
        int u = __shfl_up(v, off);
        if (lane >= off) v += u;
    }
    if (lane == 63) wsum[wid] = v;
    __syncthreads();
    if (wid == 0) {
        int s = (lane < 16) ? wsum[lane] : 0;
#pragma unroll
        for (int off = 1; off < 16; off <<= 1) {
            int u = __shfl_up(s, off);
            if (lane >= off) s += u;
        }
        if (lane < 16) wsum[lane] = s;
    }
    __syncthreads();
    int wpre = wid ? wsum[wid - 1] : 0;
    int ex = wpre + v - orig;  // exclusive prefix of this thread's pair
    cnts[i0] = ex;
    cnts[i0 + 1] = ex + v0;
    if (tid == 0) tsum[blockIdx.x] = wsum[15];
}

// K3: pass B — every block redundantly scans the 49 tile totals, adds offset.
//     Also zero-inits ovfcnt (replaces a memset dispatch).
__global__ __launch_bounds__(1024) void scan_b_kernel(const int* __restrict__ tsum,
                                                      int* __restrict__ cnts,
                                                      int* __restrict__ ovfcnt) {
    __shared__ int soff[SCAN_TILES];
    int tid = threadIdx.x, lane = tid & 63, wid = tid >> 6;
    if (blockIdx.x == 0 && tid == 0) *ovfcnt = 0;
    if (wid == 0) {
        int own = (lane < SCAN_TILES) ? tsum[lane] : 0;
        int s = own;
#pragma unroll
        for (int off = 1; off < 64; off <<= 1) {
            int u = __shfl_up(s, off);
            if (lane >= off) s += u;
        }
        if (lane < SCAN_TILES) soff[lane] = s - own;  // exclusive
    }
    __syncthreads();
    int off = soff[blockIdx.x];
    int i0 = blockIdx.x * 2048 + tid;
    cnts[i0] += off;
    cnts[i0 + 1024] += off;
}

// K4: LDS-staged COALESCED scatter. Each chunk-block sorts its 6250 records
// into bucket order in LDS, then streams them out so consecutive threads
// write consecutive global addresses (runs of ~16 records) — replaces 1.6 M
// random 8 B writes (the suspected ~6 G/s RMW path) with ~200 k run-writes.
__global__ __launch_bounds__(1024) void scatter_kernel(
        const int* __restrict__ src, const int* __restrict__ dst,
        const float* __restrict__ w, const int* __restrict__ scn,
        int2* __restrict__ rec) {
    __shared__ int h[512];      // counts -> local exclusive bases -> running pos
    __shared__ int delta[512];  // global base - local base
    __shared__ int wsum[8];
    __shared__ int2 lrec[2 * EPB];  // 6250 records, 50 KB
    int t = threadIdx.x, lane = t & 63, wid = t >> 6;
    int c = blockIdx.x;
    if (t < 512) h[t] = 0;
    __syncthreads();
    int e0 = c * EPB;
    // pass 1: local bucket counts
    for (int j = t; j < EPB; j += 1024) {
        int e = e0 + j;
        atomicAdd(&h[src[e] >> 8], 1);
        atomicAdd(&h[NB + (dst[e] >> 8)], 1);
    }
    __syncthreads();
    // exclusive scan of 512 counts (threads 0..511, one entry each)
    int v = (t < 512) ? h[t] : 0;
    int s2 = v;
#pragma unroll
    for (int off = 1; off < 64; off <<= 1) {
        int u = __shfl_up(s2, off);
        if (lane >= off) s2 += u;
    }
    if (lane == 63 && wid < 8) wsum[wid] = s2;
    __syncthreads();
    if (t == 0) {
        int r = 0;
#pragma unroll
        for (int i = 0; i < 8; ++i) { int x2 = wsum[i]; wsum[i] = r; r += x2; }
    }
    __syncthreads();
    int ex = (t < 512) ? (wsum[wid] + s2 - v) : 0;
    int gb = (t < 2 * NB) ? scn[t * NBLK + c] : 0;
    __syncthreads();  // everyone done reading h as counts
    if (t < 512) { delta[t] = gb - ex; h[t] = ex; }
    __syncthreads();
    int lb196 = h[NB];  // local start of dst-half records
    __syncthreads();
    // pass 2: place records bucket-sorted in LDS
    for (int j = t; j < EPB; j += 1024) {
        int e = e0 + j;
        int s = src[e], d = dst[e];
        int wv = __float_as_int(w[e]);
        int p0 = atomicAdd(&h[s >> 8], 1);
        lrec[p0] = make_int2(s, wv);
        int p1 = atomicAdd(&h[NB + (d >> 8)], 1);
        lrec[p1] = make_int2(s | ((d & 255) << 16) | ((d >> 8) << 24), wv);
    }
    __syncthreads();
    // pass 3: coalesced stream-out (consecutive j -> consecutive global pos)
    for (int j = t; j < 2 * EPB; j += 1024) {
        int2 r = lrec[j];
        int i = (j >= lb196) ? (NB + ((unsigned)r.x >> 24)) : ((r.x & 0xffff) >> 8);
        rec[delta[i] + j] = r;
    }
}

// K5: degw = per-bucket segmented sum of src-keyed records (1024 threads).
__global__ __launch_bounds__(1024) void degw_kernel(
        const int2* __restrict__ rec, const int* __restrict__ scn,
        float* __restrict__ degw) {
    __shared__ float acc[256];
    int t = threadIdx.x, b = blockIdx.x;
    if (t < 256) acc[t] = 0.f;
    __syncthreads();
    int s0 = scn[b * NBLK];
    int s1 = scn[(b + 1) * NBLK];  // row NB chunk-0 base == E_ for b==NB-1
    for (int j = s0 + t; j < s1; j += 1024) {
        int2 r = rec[j];
        atomicAdd(&acc[r.x & 255], __int_as_float(r.y));  // LDS fp32 atomic
    }
    __syncthreads();
    int node = b * 256 + t;
    if (t < 256 && node < N_) degw[node] = acc[t];
}

// K6: es buckets + cnt from dst-keyed records, nw inline (1024 threads).
__global__ __launch_bounds__(1024) void esbuild_kernel(
        const int2* __restrict__ rec, const int* __restrict__ scn,
        const float* __restrict__ degw, int* __restrict__ cnt,
        int2* __restrict__ es, int cap,
        int* __restrict__ ovfcnt, int4* __restrict__ ovf) {
    __shared__ int cl[256];
    __shared__ float di[256];
    int t = threadIdx.x, b = blockIdx.x;
    int node = b * 256 + t;
    if (t < 256) {
        cl[t] = 0;
        float dd = (node < N_) ? degw[node] : 0.f;
        di[t] = dd > 0.f ? rsqrtf(fmaxf(dd, 1e-12f)) : 0.f;
    }
    __syncthreads();
    int s0 = scn[(NB + b) * NBLK];
    int s1 = (b == NB - 1) ? 2 * E_ : scn[(NB + b + 1) * NBLK];
    for (int j = s0 + t; j < s1; j += 1024) {
        int2 r = rec[j];
        int s = r.x & 0xffff;          // src < 50000 fits 16 bits
        int dl = (r.x >> 16) & 255;
        float ds = degw[s];            // L2-resident random read
        float is = ds > 0.f ? rsqrtf(fmaxf(ds, 1e-12f)) : 0.f;
        float nwv = -__int_as_float(r.y) * is * di[dl];
        int rank = atomicAdd(&cl[dl], 1);  // LDS atomic
        int d = b * 256 + dl;
        if (rank < cap) {
            es[d * cap + rank] = make_int2(s, __float_as_int(nwv));
        } else {
            int op = atomicAdd(ovfcnt, 1);
            if (op < OVF_CAP) ovf[op] = make_int4(d, s, __float_as_int(nwv), 0);
        }
    }
    __syncthreads();
    if (t < 256 && node < N_) cnt[node] = cl[t];
}

// accumulate one weighted bf16x8 row-slice into acc[8]
#define ACC8(W, V)                                                       \
    acc[0] += (W) * bf2f_lo((V).x); acc[1] += (W) * bf2f_hi((V).x);      \
    acc[2] += (W) * bf2f_lo((V).y); acc[3] += (W) * bf2f_hi((V).y);      \
    acc[4] += (W) * bf2f_lo((V).z); acc[5] += (W) * bf2f_hi((V).z);      \
    acc[6] += (W) * bf2f_lo((V).w); acc[7] += (W) * bf2f_hi((V).w);

// K7: FUSED gather + node — R5's verified structure (4-deep), split into two
// dispatches via boff so aux kernels >~66 µs become visible in top-5.
__global__ __launch_bounds__(256) void gather_node_kernel(
        const int* __restrict__ cnt, const int2* __restrict__ es, int cap,
        const int* __restrict__ ovfcnt, const int4* __restrict__ ovf,
        const unsigned short* __restrict__ xb, const short* __restrict__ swz,
        const float* __restrict__ bxz, const float* __restrict__ bhz,
        const float* __restrict__ bxh, const float* __restrict__ bhh,
        const float* __restrict__ Wlin, const float* __restrict__ blin,
        float* __restrict__ out, int boff) {
    __shared__ unsigned short ltx[32 * 72];  // 32 rows x 64 ch bf16, +8 pad
    __shared__ float laz[2][16][65];         // az exchange, +1 pad

    int lane = threadIdx.x & 63;
    int wid = threadIdx.x >> 6;
    int base = (blockIdx.x + boff) * 4;

    // ---- phase 1: gather node d = base + wid (lane = t*8 + oct) ----
    {
        int d = base + wid;
        int t = lane >> 3;
        int oct = lane & 7;
        int2 pk = (lane < cap) ? es[d * cap + lane] : make_int2(0, 0);
        int m = cnt[d];
        int mb = m < cap ? m : cap;

        float acc[8] = {0.f, 0.f, 0.f, 0.f, 0.f, 0.f, 0.f, 0.f};
        const unsigned short* xbase = xb + lane * 8;  // node record = 512 shorts
        int k = 0;
        for (; k + 3 < mb; k += 4) {
            int s0 = __shfl(pk.x, k);
            int s1 = __shfl(pk.x, k + 1);
            int s2 = __shfl(pk.x, k + 2);
            int s3 = __shfl(pk.x, k + 3);
            uint4 v0 = *(const uint4*)(xbase + (long long)s0 * 512);
            uint4 v1 = *(const uint4*)(xbase + (long long)s1 * 512);
            uint4 v2 = *(const uint4*)(xbase + (long long)s2 * 512);
            uint4 v3 = *(const uint4*)(xbase + (long long)s3 * 512);
            float w0 = __int_as_float(__shfl(pk.y, k));
            float w1 = __int_as_float(__shfl(pk.y, k + 1));
            float w2 = __int_as_float(__shfl(pk.y, k + 2));
            float w3 = __int_as_float(__shfl(pk.y, k + 3));
            ACC8(w0, v0);
            ACC8(w1, v1);
            ACC8(w2, v2);
            ACC8(w3, v3);
        }
        for (; k < mb; ++k) {
            int s0 = __shfl(pk.x, k);
            float w0 = __int_as_float(__shfl(pk.y, k));
            uint4 v0 = *(const uint4*)(xbase + (long long)s0 * 512);
            ACC8(w0, v0);
        }
        if (m > cap) {  // overflow path: never taken for this input
            int oc = *ovfcnt;
            if (oc > OVF_CAP) oc = OVF_CAP;
            for (int i = 0; i < oc; ++i) {
                int4 o = ovf[i];  // uniform addr -> broadcast
                if (o.x == d) {
                    float w0 = __int_as_float(o.z);
                    uint4 v0 = *(const uint4*)(xbase + (long long)o.y * 512);
                    ACC8(w0, v0);
                }
            }
        }
        uint4 ob;
        ob.x = (unsigned int)(unsigned short)f2bf(acc[0]) |
               ((unsigned int)(unsigned short)f2bf(acc[1]) << 16);
        ob.y = (unsigned int)(unsigned short)f2bf(acc[2]) |
               ((unsigned int)(unsigned short)f2bf(acc[3]) << 16);
        ob.z = (unsigned int)(unsigned short)f2bf(acc[4]) |
               ((unsigned int)(unsigned short)f2bf(acc[5]) << 16);
        ob.w = (unsigned int)(unsigned short)f2bf(acc[6]) |
               ((unsigned int)(unsigned short)f2bf(acc[7]) << 16);
        int r = wid * 8 + t;  // block-row: r>>3 = node, r&7 = t
        *(uint4*)(ltx + r * 72 + oct * 8) = ob;
    }
    __syncthreads();

    // ---- phase 2: MFMA. wave -> (M-tile mt, gate g: 0=az, 1=ah) ----
    int mt = wid >> 1;
    int g = wid & 1;
    int c16 = lane & 15;
    int kq = lane >> 4;
    int r_blk = mt * 16 + c16;
    const unsigned short* xr = xb + (long long)(base * 8 + r_blk) * C_ + kq * 8;
    bf16x8 ax0 = *(const bf16x8*)(xr);
    bf16x8 ax1 = *(const bf16x8*)(xr + 32);
    bf16x8 at0 = *(const bf16x8*)(ltx + r_blk * 72 + kq * 8);
    bf16x8 at1 = *(const bf16x8*)(ltx + r_blk * 72 + 32 + kq * 8);

    const float* bA = g ? bxh : bxz;
    const float* bB = g ? bhh : bhz;
    const short* wA = swz + (2 * g) * 4096 + lane * 8;      // x-weight frags
    const short* wB = swz + (2 * g + 1) * 4096 + lane * 8;  // tx1-weight frags

    f32x4 a4[4];
#pragma unroll
    for (int c = 0; c < 4; ++c) {
        int col = c * 16 + c16;
        float bv = bA[col] + bB[col];
        a4[c] = (f32x4){bv, bv, bv, bv};
    }
#pragma unroll
    for (int c = 0; c < 4; ++c) {
        bf16x8 bA0 = *(const bf16x8*)(wA + (c * 2 + 0) * 512);
        bf16x8 bA1 = *(const bf16x8*)(wA + (c * 2 + 1) * 512);
        bf16x8 bB0 = *(const bf16x8*)(wB + (c * 2 + 0) * 512);
        bf16x8 bB1 = *(const bf16x8*)(wB + (c * 2 + 1) * 512);
        a4[c] = __builtin_amdgcn_mfma_f32_16x16x32_bf16(ax0, bA0, a4[c], 0, 0, 0);
        a4[c] = __builtin_amdgcn_mfma_f32_16x16x32_bf16(ax1, bA1, a4[c], 0, 0, 0);
        a4[c] = __builtin_amdgcn_mfma_f32_16x16x32_bf16(at0, bB0, a4[c], 0, 0, 0);
        a4[c] = __builtin_amdgcn_mfma_f32_16x16x32_bf16(at1, bB1, a4[c], 0, 0, 0);
    }

    // ---- phase 3: az -> LDS; ah-wave computes epilogue ----
    if (g == 0) {
#pragma unroll
        for (int c = 0; c < 4; ++c)
#pragma unroll
            for (int r = 0; r < 4; ++r)
                laz[mt][kq * 4 + r][c * 16 + c16] = a4[c][r];
    }
    __syncthreads();
    if (g == 1) {
        float part[4] = {0.f, 0.f, 0.f, 0.f};
#pragma unroll
        for (int c = 0; c < 4; ++c) {
            int col = c * 16 + c16;
            float wl = Wlin[col];
#pragma unroll
            for (int r = 0; r < 4; ++r) {
                float a = laz[mt][kq * 4 + r][col];
                float b = a4[c][r];
                float z = 1.f / (1.f + __expf(-a));
                float aa = fabsf(b);
                float e = __expf(-2.f * aa);
                float ht = copysignf((1.f - e) / (1.f + e), b);
                float h = fmaxf((1.f - z) * ht, 0.f);
                part[r] += h * wl;
            }
        }
#pragma unroll
        for (int m = 1; m <= 8; m <<= 1) {
#pragma unroll
            for (int r = 0; r < 4; ++r) part[r] += __shfl_xor(part[r], m);
        }
        if (c16 == 0) {
            float bl = blin[0];
#pragma unroll
            for (int r = 0; r < 4; ++r) {
                int rb = mt * 16 + kq * 4 + r;
                out[(long long)(rb & 7) * N_ + base + (rb >> 3)] = part[r] + bl;
            }
        }
    }
}

extern "C" void kernel_launch(void* const* d_in, const int* in_sizes, int n_in,
                              void* d_out, int out_size, void* d_ws, size_t ws_size,
                              hipStream_t stream) {
    const float* x    = (const float*)d_in[0];
    const int*   ei   = (const int*)d_in[1];
    const float* w    = (const float*)d_in[2];
    const float* Wxz0 = (const float*)d_in[3];
    const float* Wxz1 = (const float*)d_in[4];
    const float* bxz  = (const float*)d_in[5];
    const float* bhz  = (const float*)d_in[8];
    const float* Wxh0 = (const float*)d_in[15];
    const float* Wxh1 = (const float*)d_in[16];
    const float* bxh  = (const float*)d_in[17];
    const float* bhh  = (const float*)d_in[20];
    const float* Wlin = (const float*)d_in[21];
    const float* blin = (const float*)d_in[22];
    float* out = (float*)d_out;

    const int* src = ei;
    const int* dst = ei + E_;

    // workspace layout (512-aligned blocks):
    char* ws = (char*)d_ws;
    size_t off = 0;
    auto alloc = [&](size_t bytes) {
        char* p = ws + off;
        off = (off + bytes + 511) & ~(size_t)511;
        return p;
    };
    short* swz         = (short*)alloc(4 * 4096 * sizeof(short));           // 32 KB
    float* degw        = (float*)alloc((size_t)N_ * 4);                     // 200 KB
    int*   cnt         = (int*)alloc((size_t)N_ * 4);                       // 200 KB
    int*   ovfcnt      = (int*)alloc(512);
    int4*  ovf         = (int4*)alloc((size_t)OVF_CAP * 16);                // 2 MB
    int*   counts      = (int*)alloc((size_t)SCN * 4);                      // 401 KB
    int*   tsum        = (int*)alloc((size_t)SCAN_TILES * 4);
    int2*  rec         = (int2*)alloc((size_t)2 * E_ * 8);                  // 12.8 MB
    unsigned short* xb = (unsigned short*)alloc((size_t)T_ * N_ * C_ * 2);  // 51.2 MB
    size_t fixed = off;

    // pick the largest bucket capacity that fits the workspace
    int cap = 16;
    for (int c : {64, 48, 32, 24}) {
        if (fixed + (size_t)N_ * c * 8 + 512 <= ws_size) { cap = c; break; }
    }
    int2* es = (int2*)alloc((size_t)N_ * cap * 8);

    // K1: hist (256) + xcvt (12500) + wprep (64)
    prep_kernel<<<NBLK + 12500 + 64, 256, 0, stream>>>(
        src, dst, counts, x, xb, Wxz0, Wxz1, Wxh0, Wxh1, swz);

    // K2/K3: exclusive scan of the 100352-entry count matrix (+ovfcnt init)
    scan_a_kernel<<<SCAN_TILES, 1024, 0, stream>>>(counts, tsum);
    scan_b_kernel<<<SCAN_TILES, 1024, 0, stream>>>(tsum, counts, ovfcnt);

    // K4: LDS-staged coalesced scatter
    scatter_kernel<<<NBLK, 1024, 0, stream>>>(src, dst, w, counts, rec);

    // K5: degw segmented reduce
    degw_kernel<<<NB, 1024, 0, stream>>>(rec, counts, degw);

    // K6: es buckets + cnt + inline nw
    esbuild_kernel<<<NB, 1024, 0, stream>>>(rec, counts, degw, cnt,
                                            es, cap, ovfcnt, ovf);

    // K7: gather split in two 6250-block halves (diagnostic visibility)
    gather_node_kernel<<<6250, 256, 0, stream>>>(
        cnt, es, cap, ovfcnt, ovf, xb, swz,
        bxz, bhz, bxh, bhh, Wlin, blin, out, 0);
    gather_node_kernel<<<6250, 256, 0, stream>>>(
        cnt, es, cap, ovfcnt, ovf, xb, swz,
        bxz, bhz, bxh, bhh, Wlin, blin, out, 6250);
}

// Round 9
// 347.058 us; speedup vs baseline: 4.3101x; 1.0601x over previous
//
#include <hip/hip_runtime.h>

#define T_ 8
#define N_ 50000
#define E_ 800000
#define C_ 64
#define OVF_CAP 65536
#define NB 196     // node buckets (256 nodes each, 196*256 = 50176 >= N)
#define NBLK 256   // edge chunks (256*3125 = 800000 exactly)
#define EPB 3125   // edges per chunk
#define BCAP 6144  // per-bucket run capacity (mean fill 4082, sigma ~64: +32 sigma)

typedef __attribute__((ext_vector_type(8))) short bf16x8;
typedef __attribute__((ext_vector_type(4))) float f32x4;

__device__ inline short f2bf(float f) {
    union { float f; unsigned int u; } v; v.f = f;
    unsigned int u = v.u + 0x7FFFu + ((v.u >> 16) & 1u);  // RNE
    return (short)(u >> 16);
}
__device__ inline float bf2f_lo(unsigned int u) {
    union { unsigned int u; float f; } v; v.u = u << 16;
    return v.f;
}
__device__ inline float bf2f_hi(unsigned int u) {
    union { unsigned int u; float f; } v; v.u = u & 0xffff0000u;
    return v.f;
}

// xcvt helper: convert one (n,t,c8) slice to node-major bf16 xb
__device__ inline void xcvt_step(int id, const float* __restrict__ x,
                                 unsigned short* __restrict__ xb) {
    int c8 = id & 7;
    int t = (id >> 3) & 7;
    int n = id >> 6;
    const float* xr = x + ((long long)t * N_ + n) * C_ + c8 * 8;
    float4 a = *(const float4*)(xr);
    float4 b = *(const float4*)(xr + 4);
    bf16x8 o;
    o[0] = f2bf(a.x); o[1] = f2bf(a.y); o[2] = f2bf(a.z); o[3] = f2bf(a.w);
    o[4] = f2bf(b.x); o[5] = f2bf(b.y); o[6] = f2bf(b.z); o[7] = f2bf(b.w);
    *(bf16x8*)(xb + (long long)id * 8) = o;  // node-major [n][t][c]
}

// ---------------------------------------------------------------------------
// K1 (mega): scatter-with-run-reservation (blocks [0,NBLK)) + xcvt + wprep.
// Run reservation kills the hist pass + both scan kernels: each chunk counts
// its 392-bucket histogram in LDS, reserves contiguous runs with ONE packed
// 64-bit atomicAdd per bucket-pair (196/block, 50 k total), LDS-sorts its
// 6250 records, and streams them out coalesced into the reserved runs.
__global__ __launch_bounds__(1024) void mega_prep_kernel(
        const int* __restrict__ src, const int* __restrict__ dst,
        const float* __restrict__ w,
        unsigned long long* __restrict__ cursor,
        int* __restrict__ ovfAcnt, int4* __restrict__ ovfA,
        int2* __restrict__ rec,
        const float* __restrict__ x, unsigned short* __restrict__ xb,
        const float* __restrict__ Wz0, const float* __restrict__ Wz1,
        const float* __restrict__ Wh0, const float* __restrict__ Wh1,
        short* __restrict__ swz) {
    int t = threadIdx.x;
    if (blockIdx.x < NBLK) {
        __shared__ int h[512];       // counts -> local bases -> running pos
        __shared__ int delta[512];   // bucket-relative global base - local base
        __shared__ int wsum[16];
        __shared__ unsigned long long gres[NB];
        __shared__ int2 lrec[2 * EPB];  // 50 KB
        int lane = t & 63, wid = t >> 6;
        int c = blockIdx.x;
        if (t < 512) h[t] = 0;
        __syncthreads();
        int e0 = c * EPB;
        // pass 1: local bucket counts
        for (int j = t; j < EPB; j += 1024) {
            int e = e0 + j;
            atomicAdd(&h[src[e] >> 8], 1);
            atomicAdd(&h[NB + (dst[e] >> 8)], 1);
        }
        __syncthreads();
        int v = (t < 512) ? h[t] : 0;
        // packed run reservation: src bucket t (low 32) + dst bucket t (high 32)
        if (t < NB) {
            unsigned long long add =
                ((unsigned long long)(unsigned)h[NB + t] << 32) | (unsigned)h[t];
            gres[t] = atomicAdd(&cursor[t], add);
        }
        // local exclusive scan of the 512 counts
        int s2 = v;
#pragma unroll
        for (int off = 1; off < 64; off <<= 1) {
            int u = __shfl_up(s2, off);
            if (lane >= off) s2 += u;
        }
        if (lane == 63) wsum[wid] = s2;
        __syncthreads();
        if (t == 0) {
            int r = 0;
#pragma unroll
            for (int i = 0; i < 16; ++i) { int x2 = wsum[i]; wsum[i] = r; r += x2; }
        }
        __syncthreads();
        int ex = wsum[wid] + s2 - v;  // local exclusive base (valid t<512)
        if (t < 512) {
            int gb = (t < NB) ? (int)(gres[t] & 0xffffffffULL)
                              : (int)(gres[t - NB] >> 32);
            delta[t] = gb - ex;
            h[t] = ex;
        }
        __syncthreads();
        // pass 2: place records bucket-sorted in LDS
        for (int j = t; j < EPB; j += 1024) {
            int e = e0 + j;
            int s = src[e], d = dst[e];
            int wv = __float_as_int(w[e]);
            int p0 = atomicAdd(&h[s >> 8], 1);
            lrec[p0] = make_int2(s, wv);
            int p1 = atomicAdd(&h[NB + (d >> 8)], 1);
            lrec[p1] = make_int2(s | ((d & 255) << 16) | ((d >> 8) << 24), wv);
        }
        __syncthreads();
        // pass 3: coalesced stream-out into reserved runs (src-half = [0,EPB))
        for (int j = t; j < 2 * EPB; j += 1024) {
            int2 r = lrec[j];
            int isd = (j >= EPB);
            int i = isd ? (NB + (int)((unsigned)r.x >> 24)) : ((r.x & 0xffff) >> 8);
            int rel = delta[i] + j;  // bucket-relative global offset
            if (rel < BCAP) {
                rec[(long long)i * BCAP + rel] = r;
            } else {  // ~32-sigma event: spill, consumed by degw/esbuild
                int op = atomicAdd(ovfAcnt, 1);
                if (op < OVF_CAP) ovfA[op] = make_int4(isd, r.x, r.y, 0);
            }
        }
    } else if (blockIdx.x < NBLK + 3125) {
        int id = (blockIdx.x - NBLK) * 1024 + t;
        xcvt_step(id, x, xb);
    } else {
        int idx = (blockIdx.x - NBLK - 3125) * 1024 + t;  // < 16384
        int j = idx & 7;
        int lane = (idx >> 3) & 63;
        int kb = (idx >> 9) & 1;
        int c = (idx >> 10) & 3;
        int mat = idx >> 12;
        const float* W = (mat == 0) ? Wz0 : (mat == 1) ? Wz1 : (mat == 2) ? Wh0 : Wh1;
        int k = kb * 32 + (lane >> 4) * 8 + j;
        int n = c * 16 + (lane & 15);
        swz[idx] = f2bf(W[k * 64 + n]);
    }
}

// K2: degw = per-bucket segmented sum of src-keyed run (+ ovfA spill handling).
__global__ __launch_bounds__(1024) void degw_kernel(
        const int2* __restrict__ rec, const unsigned long long* __restrict__ cursor,
        const int* __restrict__ ovfAcnt, const int4* __restrict__ ovfA,
        float* __restrict__ degw) {
    __shared__ float acc[256];
    int t = threadIdx.x, b = blockIdx.x;
    if (t < 256) acc[t] = 0.f;
    __syncthreads();
    int fill = (int)(cursor[b] & 0xffffffffULL);
    if (fill > BCAP) fill = BCAP;
    const int2* base = rec + (long long)b * BCAP;
    for (int j = t; j < fill; j += 1024) {
        int2 r = base[j];
        atomicAdd(&acc[r.x & 255], __int_as_float(r.y));  // LDS fp32 atomic
    }
    __syncthreads();
    if (t == 0) {  // spill records (normally zero)
        int oc = *ovfAcnt;
        if (oc > OVF_CAP) oc = OVF_CAP;
        for (int i = 0; i < oc; ++i) {
            int4 o = ovfA[i];
            if (o.x == 0) {
                int s = o.y & 0xffff;
                if ((s >> 8) == b) acc[s & 255] += __int_as_float(o.z);
            }
        }
    }
    __syncthreads();
    int node = b * 256 + t;
    if (t < 256 && node < N_) degw[node] = acc[t];
}

// K3: es buckets + cnt from dst-keyed run, nw inline (+ ovfA spill handling).
__global__ __launch_bounds__(1024) void esbuild_kernel(
        const int2* __restrict__ rec, const unsigned long long* __restrict__ cursor,
        const float* __restrict__ degw, int* __restrict__ cnt,
        int2* __restrict__ es, int cap,
        const int* __restrict__ ovfAcnt, const int4* __restrict__ ovfA,
        int* __restrict__ ovfBcnt, int4* __restrict__ ovfB) {
    __shared__ int cl[256];
    __shared__ float di[256];
    int t = threadIdx.x, b = blockIdx.x;
    int node = b * 256 + t;
    if (t < 256) {
        cl[t] = 0;
        float dd = (node < N_) ? degw[node] : 0.f;
        di[t] = dd > 0.f ? rsqrtf(fmaxf(dd, 1e-12f)) : 0.f;
    }
    __syncthreads();
    int fill = (int)(cursor[b] >> 32);
    if (fill > BCAP) fill = BCAP;
    const int2* base = rec + (long long)(NB + b) * BCAP;
    for (int j = t; j < fill; j += 1024) {
        int2 r = base[j];
        int s = r.x & 0xffff;          // src < 50000 fits 16 bits
        int dl = (r.x >> 16) & 255;
        float ds = degw[s];            // L2-resident random read
        float is = ds > 0.f ? rsqrtf(fmaxf(ds, 1e-12f)) : 0.f;
        float nwv = -__int_as_float(r.y) * is * di[dl];
        int rank = atomicAdd(&cl[dl], 1);  // LDS atomic
        int d = b * 256 + dl;
        if (rank < cap) {
            es[d * cap + rank] = make_int2(s, __float_as_int(nwv));
        } else {
            int op = atomicAdd(ovfBcnt, 1);
            if (op < OVF_CAP) ovfB[op] = make_int4(d, s, __float_as_int(nwv), 0);
        }
    }
    __syncthreads();
    if (t == 0) {  // spill records (normally zero)
        int oc = *ovfAcnt;
        if (oc > OVF_CAP) oc = OVF_CAP;
        for (int i = 0; i < oc; ++i) {
            int4 o = ovfA[i];
            if (o.x == 1) {
                int dh = (int)((unsigned)o.y >> 24);
                if (dh == b) {
                    int s = o.y & 0xffff;
                    int dl = (o.y >> 16) & 255;
                    float ds = degw[s];
                    float is = ds > 0.f ? rsqrtf(fmaxf(ds, 1e-12f)) : 0.f;
                    float nwv = -__int_as_float(o.z) * is * di[dl];
                    int rank = cl[dl]++;
                    int d = b * 256 + dl;
                    if (rank < cap) {
                        es[d * cap + rank] = make_int2(s, __float_as_int(nwv));
                    } else {
                        int op = atomicAdd(ovfBcnt, 1);
                        if (op < OVF_CAP) ovfB[op] = make_int4(d, s, __float_as_int(nwv), 0);
                    }
                }
            }
        }
    }
    __syncthreads();
    if (t < 256 && node < N_) cnt[node] = cl[t];
}

// accumulate one weighted bf16x8 row-slice into acc[8]
#define ACC8(W, V)                                                       \
    acc[0] += (W) * bf2f_lo((V).x); acc[1] += (W) * bf2f_hi((V).x);      \
    acc[2] += (W) * bf2f_lo((V).y); acc[3] += (W) * bf2f_hi((V).y);      \
    acc[4] += (W) * bf2f_lo((V).z); acc[5] += (W) * bf2f_hi((V).z);      \
    acc[6] += (W) * bf2f_lo((V).w); acc[7] += (W) * bf2f_hi((V).w);

// K4: FUSED gather + node — R5's verified 128 µs structure, single dispatch.
__global__ __launch_bounds__(256) void gather_node_kernel(
        const int* __restrict__ cnt, const int2* __restrict__ es, int cap,
        const int* __restrict__ ovfcnt, const int4* __restrict__ ovf,
        const unsigned short* __restrict__ xb, const short* __restrict__ swz,
        const float* __restrict__ bxz, const float* __restrict__ bhz,
        const float* __restrict__ bxh, const float* __restrict__ bhh,
        const float* __restrict__ Wlin, const float* __restrict__ blin,
        float* __restrict__ out) {
    __shared__ unsigned short ltx[32 * 72];  // 32 rows x 64 ch bf16, +8 pad
    __shared__ float laz[2][16][65];         // az exchange, +1 pad

    int lane = threadIdx.x & 63;
    int wid = threadIdx.x >> 6;
    int base = blockIdx.x * 4;

    // ---- phase 1: gather node d = base + wid (lane = t*8 + oct) ----
    {
        int d = base + wid;
        int t = lane >> 3;
        int oct = lane & 7;
        int2 pk = (lane < cap) ? es[d * cap + lane] : make_int2(0, 0);
        int m = cnt[d];
        int mb = m < cap ? m : cap;

        float acc[8] = {0.f, 0.f, 0.f, 0.f, 0.f, 0.f, 0.f, 0.f};
        const unsigned short* xbase = xb + lane * 8;  // node record = 512 shorts
        int k = 0;
        for (; k + 3 < mb; k += 4) {
            int s0 = __shfl(pk.x, k);
            int s1 = __shfl(pk.x, k + 1);
            int s2 = __shfl(pk.x, k + 2);
            int s3 = __shfl(pk.x, k + 3);
            uint4 v0 = *(const uint4*)(xbase + (long long)s0 * 512);
            uint4 v1 = *(const uint4*)(xbase + (long long)s1 * 512);
            uint4 v2 = *(const uint4*)(xbase + (long long)s2 * 512);
            uint4 v3 = *(const uint4*)(xbase + (long long)s3 * 512);
            float w0 = __int_as_float(__shfl(pk.y, k));
            float w1 = __int_as_float(__shfl(pk.y, k + 1));
            float w2 = __int_as_float(__shfl(pk.y, k + 2));
            float w3 = __int_as_float(__shfl(pk.y, k + 3));
            ACC8(w0, v0);
            ACC8(w1, v1);
            ACC8(w2, v2);
            ACC8(w3, v3);
        }
        for (; k < mb; ++k) {
            int s0 = __shfl(pk.x, k);
            float w0 = __int_as_float(__shfl(pk.y, k));
            uint4 v0 = *(const uint4*)(xbase + (long long)s0 * 512);
            ACC8(w0, v0);
        }
        if (m > cap) {  // overflow path: never taken for this input
            int oc = *ovfcnt;
            if (oc > OVF_CAP) oc = OVF_CAP;
            for (int i = 0; i < oc; ++i) {
                int4 o = ovf[i];  // uniform addr -> broadcast
                if (o.x == d) {
                    float w0 = __int_as_float(o.z);
                    uint4 v0 = *(const uint4*)(xbase + (long long)o.y * 512);
                    ACC8(w0, v0);
                }
            }
        }
        uint4 ob;
        ob.x = (unsigned int)(unsigned short)f2bf(acc[0]) |
               ((unsigned int)(unsigned short)f2bf(acc[1]) << 16);
        ob.y = (unsigned int)(unsigned short)f2bf(acc[2]) |
               ((unsigned int)(unsigned short)f2bf(acc[3]) << 16);
        ob.z = (unsigned int)(unsigned short)f2bf(acc[4]) |
               ((unsigned int)(unsigned short)f2bf(acc[5]) << 16);
        ob.w = (unsigned int)(unsigned short)f2bf(acc[6]) |
               ((unsigned int)(unsigned short)f2bf(acc[7]) << 16);
        int r = wid * 8 + t;  // block-row: r>>3 = node, r&7 = t
        *(uint4*)(ltx + r * 72 + oct * 8) = ob;
    }
    __syncthreads();

    // ---- phase 2: MFMA. wave -> (M-tile mt, gate g: 0=az, 1=ah) ----
    int mt = wid >> 1;
    int g = wid & 1;
    int c16 = lane & 15;
    int kq = lane >> 4;
    int r_blk = mt * 16 + c16;
    const unsigned short* xr = xb + (long long)(base * 8 + r_blk) * C_ + kq * 8;
    bf16x8 ax0 = *(const bf16x8*)(xr);
    bf16x8 ax1 = *(const bf16x8*)(xr + 32);
    bf16x8 at0 = *(const bf16x8*)(ltx + r_blk * 72 + kq * 8);
    bf16x8 at1 = *(const bf16x8*)(ltx + r_blk * 72 + 32 + kq * 8);

    const float* bA = g ? bxh : bxz;
    const float* bB = g ? bhh : bhz;
    const short* wA = swz + (2 * g) * 4096 + lane * 8;      // x-weight frags
    const short* wB = swz + (2 * g + 1) * 4096 + lane * 8;  // tx1-weight frags

    f32x4 a4[4];
#pragma unroll
    for (int c = 0; c < 4; ++c) {
        int col = c * 16 + c16;
        float bv = bA[col] + bB[col];
        a4[c] = (f32x4){bv, bv, bv, bv};
    }
#pragma unroll
    for (int c = 0; c < 4; ++c) {
        bf16x8 bA0 = *(const bf16x8*)(wA + (c * 2 + 0) * 512);
        bf16x8 bA1 = *(const bf16x8*)(wA + (c * 2 + 1) * 512);
        bf16x8 bB0 = *(const bf16x8*)(wB + (c * 2 + 0) * 512);
        bf16x8 bB1 = *(const bf16x8*)(wB + (c * 2 + 1) * 512);
        a4[c] = __builtin_amdgcn_mfma_f32_16x16x32_bf16(ax0, bA0, a4[c], 0, 0, 0);
        a4[c] = __builtin_amdgcn_mfma_f32_16x16x32_bf16(ax1, bA1, a4[c], 0, 0, 0);
        a4[c] = __builtin_amdgcn_mfma_f32_16x16x32_bf16(at0, bB0, a4[c], 0, 0, 0);
        a4[c] = __builtin_amdgcn_mfma_f32_16x16x32_bf16(at1, bB1, a4[c], 0, 0, 0);
    }

    // ---- phase 3: az -> LDS; ah-wave computes epilogue ----
    if (g == 0) {
#pragma unroll
        for (int c = 0; c < 4; ++c)
#pragma unroll
            for (int r = 0; r < 4; ++r)
                laz[mt][kq * 4 + r][c * 16 + c16] = a4[c][r];
    }
    __syncthreads();
    if (g == 1) {
        float part[4] = {0.f, 0.f, 0.f, 0.f};
#pragma unroll
        for (int c = 0; c < 4; ++c) {
            int col = c * 16 + c16;
            float wl = Wlin[col];
#pragma unroll
            for (int r = 0; r < 4; ++r) {
                float a = laz[mt][kq * 4 + r][col];
                float b = a4[c][r];
                float z = 1.f / (1.f + __expf(-a));
                float aa = fabsf(b);
                float e = __expf(-2.f * aa);
                float ht = copysignf((1.f - e) / (1.f + e), b);
                float h = fmaxf((1.f - z) * ht, 0.f);
                part[r] += h * wl;
            }
        }
#pragma unroll
        for (int m = 1; m <= 8; m <<= 1) {
#pragma unroll
            for (int r = 0; r < 4; ++r) part[r] += __shfl_xor(part[r], m);
        }
        if (c16 == 0) {
            float bl = blin[0];
#pragma unroll
            for (int r = 0; r < 4; ++r) {
                int rb = mt * 16 + kq * 4 + r;
                out[(long long)(rb & 7) * N_ + base + (rb >> 3)] = part[r] + bl;
            }
        }
    }
}

extern "C" void kernel_launch(void* const* d_in, const int* in_sizes, int n_in,
                              void* d_out, int out_size, void* d_ws, size_t ws_size,
                              hipStream_t stream) {
    const float* x    = (const float*)d_in[0];
    const int*   ei   = (const int*)d_in[1];
    const float* w    = (const float*)d_in[2];
    const float* Wxz0 = (const float*)d_in[3];
    const float* Wxz1 = (const float*)d_in[4];
    const float* bxz  = (const float*)d_in[5];
    const float* bhz  = (const float*)d_in[8];
    const float* Wxh0 = (const float*)d_in[15];
    const float* Wxh1 = (const float*)d_in[16];
    const float* bxh  = (const float*)d_in[17];
    const float* bhh  = (const float*)d_in[20];
    const float* Wlin = (const float*)d_in[21];
    const float* blin = (const float*)d_in[22];
    float* out = (float*)d_out;

    const int* src = ei;
    const int* dst = ei + E_;

    // workspace layout (512-aligned blocks):
    char* ws = (char*)d_ws;
    size_t off = 0;
    auto alloc = [&](size_t bytes) {
        char* p = ws + off;
        off = (off + bytes + 511) & ~(size_t)511;
        return p;
    };
    short* swz         = (short*)alloc(4 * 4096 * sizeof(short));           // 32 KB
    float* degw        = (float*)alloc((size_t)N_ * 4);                     // 200 KB
    int*   cnt         = (int*)alloc((size_t)N_ * 4);                       // 200 KB
    char*  ctr         = (char*)alloc(4096);                                // cursors + ovf counters
    unsigned long long* cursor = (unsigned long long*)ctr;                  // 196 x 8 B
    int*   ovfAcnt     = (int*)(ctr + 2048);
    int*   ovfBcnt     = (int*)(ctr + 2560);
    int4*  ovfA        = (int4*)alloc((size_t)OVF_CAP * 16);                // 1 MB
    int4*  ovfB        = (int4*)alloc((size_t)OVF_CAP * 16);                // 1 MB
    int2*  rec         = (int2*)alloc((size_t)2 * NB * BCAP * 8);           // 19.3 MB
    unsigned short* xb = (unsigned short*)alloc((size_t)T_ * N_ * C_ * 2);  // 51.2 MB
    size_t fixed = off;

    // pick the largest bucket capacity that fits the workspace
    int cap = 16;
    for (int c : {64, 48, 32, 24}) {
        if (fixed + (size_t)N_ * c * 8 + 512 <= ws_size) { cap = c; break; }
    }
    int2* es = (int2*)alloc((size_t)N_ * cap * 8);

    // zero the cursors + overflow counters (one tiny memset)
    hipMemsetAsync(ctr, 0, 4096, stream);

    // K1: scatter (256) + xcvt (3125 x 1024 thr) + wprep (16) = 3397 blocks
    mega_prep_kernel<<<NBLK + 3125 + 16, 1024, 0, stream>>>(
        src, dst, w, cursor, ovfAcnt, ovfA, rec,
        x, xb, Wxz0, Wxz1, Wxh0, Wxh1, swz);

    // K2: degw segmented reduce over src-keyed runs
    degw_kernel<<<NB, 1024, 0, stream>>>(rec, cursor, ovfAcnt, ovfA, degw);

    // K3: es buckets + cnt + inline nw over dst-keyed runs
    esbuild_kernel<<<NB, 1024, 0, stream>>>(rec, cursor, degw, cnt, es, cap,
                                            ovfAcnt, ovfA, ovfBcnt, ovfB);

    // K4: gather, single dispatch: 12500 blocks x 4 nodes = 50000
    gather_node_kernel<<<N_ / 4, 256, 0, stream>>>(
        cnt, es, cap, ovfBcnt, ovfB, xb, swz,
        bxz, bhz, bxh, bhh, Wlin, blin, out);
}